// Round 5
// baseline (393.740 us; speedup 1.0000x reference)
//
#include <hip/hip_runtime.h>
#include <hip/hip_bf16.h>

#define S_LEN 2048
#define NBATCH 2
#define DMODEL 1024
#define NHEAD 16
#define NKV 4
#define HDIM 64

typedef __attribute__((ext_vector_type(4))) float f32x4;
typedef __attribute__((ext_vector_type(8))) short s16x8;

// 0.125 (1/sqrt(dk)) * log2(e): Q pre-scale so softmax runs in exp2 domain
#define QSCALE 0.18033688011112042f

__device__ __forceinline__ unsigned short f32_bf16(float f) {
    unsigned int u = __float_as_uint(f);
    u += 0x7FFFu + ((u >> 16) & 1u);
    return (unsigned short)(u >> 16);
}

// ---------------- f32 -> bf16 convert ----------------
__global__ __launch_bounds__(256) void cvt_bf16_k(const float* __restrict__ in,
                                                  unsigned short* __restrict__ out, int n4) {
    int i = blockIdx.x * 256 + threadIdx.x;
    if (i < n4) {
        const float4 v = reinterpret_cast<const float4*>(in)[i];
        ushort4 r;
        r.x = f32_bf16(v.x); r.y = f32_bf16(v.y);
        r.z = f32_bf16(v.z); r.w = f32_bf16(v.w);
        reinterpret_cast<ushort4*>(out)[i] = r;
    }
}

// ---------------- GEMM: C[M][N] = A[M][K] @ W[K][N], bf16 in, f32 acc ----------------
// EPI 0: f32 row-major out.
// EPI 1: rope + *oscale + bf16 head-layout [B][nheads][S][DK].
// EPI 3: bf16 TRANSPOSED head-layout [B][nheads][DK][S]  (for V)
template<int EPI>
__global__ __launch_bounds__(256) void gemm_k(
    const unsigned short* __restrict__ A,
    const unsigned short* __restrict__ W,
    void* __restrict__ Out, int N, int K, int nheads, float oscale)
{
    __shared__ unsigned short As[64][72];   // [m][k], +8 pad
    __shared__ unsigned short Bs[64][72];   // [n][k] (transposed), +8 pad

    const int tid  = threadIdx.x;
    const int lane = tid & 63;
    const int l15  = lane & 15;
    const int l4   = lane >> 4;
    const int wave = tid >> 6;
    const int wr   = (wave >> 1) * 32;
    const int wc   = (wave & 1) * 32;
    const int bm   = blockIdx.y * 64;
    const int bn   = blockIdx.x * 64;

    f32x4 acc[2][2] = {};

    for (int k0 = 0; k0 < K; k0 += 64) {
        #pragma unroll
        for (int cc = 0; cc < 2; ++cc) {
            const int c   = tid + cc * 256;      // 512 chunks of 8 elems
            const int row = c >> 3;
            const int col = (c & 7) * 8;
            *reinterpret_cast<s16x8*>(&As[row][col]) =
                *reinterpret_cast<const s16x8*>(A + (size_t)(bm + row) * K + k0 + col);
            const s16x8 wv =
                *reinterpret_cast<const s16x8*>(W + (size_t)(k0 + row) * N + bn + col);
            #pragma unroll
            for (int i = 0; i < 8; ++i) Bs[col + i][row] = (short)wv[i];
        }
        __syncthreads();
        #pragma unroll
        for (int ks = 0; ks < 2; ++ks) {
            s16x8 af[2], bfv[2];
            #pragma unroll
            for (int i = 0; i < 2; ++i)
                af[i] = *reinterpret_cast<const s16x8*>(&As[wr + i*16 + l15][ks*32 + l4*8]);
            #pragma unroll
            for (int j = 0; j < 2; ++j)
                bfv[j] = *reinterpret_cast<const s16x8*>(&Bs[wc + j*16 + l15][ks*32 + l4*8]);
            #pragma unroll
            for (int i = 0; i < 2; ++i)
                #pragma unroll
                for (int j = 0; j < 2; ++j)
                    acc[i][j] = __builtin_amdgcn_mfma_f32_16x16x32_bf16(
                        af[i], bfv[j], acc[i][j], 0, 0, 0);
        }
        __syncthreads();
    }

    #pragma unroll
    for (int i = 0; i < 2; ++i) {
        #pragma unroll
        for (int j = 0; j < 2; ++j) {
            #pragma unroll
            for (int v = 0; v < 4; ++v) {
                const int gr = bm + wr + i*16 + l4*4 + v;
                const int gc = bn + wc + j*16 + l15;
                float val = acc[i][j][v];
                if (EPI == 0) {
                    reinterpret_cast<float*>(Out)[(size_t)gr * N + gc] = val;
                } else {
                    if (EPI == 1) {
                        const float partner = __shfl_xor(val, 1, 64);
                        const int   jp = (gc & 63) >> 1;      // pair index 0..31
                        const int   hh = gc >> 6;             // head index
                        // inv_freq = 10000^(-2*jp/64)
                        const float inv = __expf((float)jp * (-2.0f / 64.0f) * 9.210340371976184f);
                        const float ang = (float)hh * inv;
                        float sn, cs;
                        __sincosf(ang, &sn, &cs);
                        val = ((gc & 1) == 0) ? (val * cs - partner * sn)
                                              : (partner * sn + val * cs);
                        val *= oscale;
                    }
                    const int b  = gr >> 11;       // / S_LEN
                    const int sr = gr & (S_LEN - 1);
                    const int hh = gc >> 6;
                    const int dk = gc & 63;
                    if (EPI == 3) {
                        reinterpret_cast<unsigned short*>(Out)[
                            (((size_t)b * nheads + hh) * HDIM + dk) * S_LEN + sr] = f32_bf16(val);
                    } else {
                        reinterpret_cast<unsigned short*>(Out)[
                            (((size_t)b * nheads + hh) * S_LEN + sr) * HDIM + dk] = f32_bf16(val);
                    }
                }
            }
        }
    }
}

// ---------------- flash attention (causal, GQA), swapped-operand form ----------------
// Q: [B][NHEAD][S][DK] bf16 (rope+QSCALE applied), K: [B][NKV][S][DK],
// Vt: [B][NKV][DK][S] (transposed), Ctx out: [B][S][NHEAD][DK] bf16.
// QK^T computed as mfma(K,Q) -> D = S^T[kv][q]: lane owns ONE q (=lane&15).
// Register double-buffered K/V prefetch hides L2/L3 latency; equal-work
// causal tile pairing (t, 31-t) removes the occupancy tail.

__device__ __forceinline__ void load_kv(
    const unsigned short* __restrict__ Kp,
    const unsigned short* __restrict__ Vp,
    int kv0, int l15, int l4, s16x8 (&kf)[4][2], s16x8 (&vf)[4][2])
{
    #pragma unroll
    for (int c = 0; c < 4; ++c)
        #pragma unroll
        for (int ks = 0; ks < 2; ++ks)
            kf[c][ks] = *reinterpret_cast<const s16x8*>(
                Kp + (size_t)(kv0 + c*16 + l15) * HDIM + ks*32 + l4*8);
    #pragma unroll
    for (int dkc = 0; dkc < 4; ++dkc)
        #pragma unroll
        for (int ks = 0; ks < 2; ++ks)
            vf[dkc][ks] = *reinterpret_cast<const s16x8*>(
                Vp + (size_t)(dkc*16 + l15) * S_LEN + kv0 + ks*32 + l4*8);
}

template<bool MASK>
__device__ __forceinline__ void attn_compute(
    int kv0, int qb, int l15, int l4,
    const s16x8 (&kf)[4][2], const s16x8 (&vf)[4][2],
    const s16x8 qf[2], f32x4 o[4], float& m, float& lsum,
    unsigned short (*Plds)[80])
{
    // ---- S^T[kv][q]: lane holds kv = c*16 + l4*4 + v for q = l15 ----
    f32x4 s[4] = {};
    #pragma unroll
    for (int c = 0; c < 4; ++c)
        #pragma unroll
        for (int ks = 0; ks < 2; ++ks)
            s[c] = __builtin_amdgcn_mfma_f32_16x16x32_bf16(kf[c][ks], qf[ks], s[c], 0, 0, 0);

    if (MASK) {
        const int qg = qb + l15;
        #pragma unroll
        for (int c = 0; c < 4; ++c)
            #pragma unroll
            for (int v = 0; v < 4; ++v) {
                const int kvg = kv0 + c*16 + l4*4 + v;
                s[c][v] = (kvg <= qg) ? s[c][v] : -1e30f;
            }
    }

    // ---- online softmax, lane-local + 2-shuffle cross-l4 reduce ----
    float mx = -1e30f;
    #pragma unroll
    for (int c = 0; c < 4; ++c)
        #pragma unroll
        for (int v = 0; v < 4; ++v) mx = fmaxf(mx, s[c][v]);
    mx = fmaxf(mx, __shfl_xor(mx, 16, 64));
    mx = fmaxf(mx, __shfl_xor(mx, 32, 64));
    const float mnew  = fmaxf(m, mx);
    const float scale = __builtin_amdgcn_exp2f(m - mnew);
    float psum = 0.0f;
    #pragma unroll
    for (int c = 0; c < 4; ++c)
        #pragma unroll
        for (int v = 0; v < 4; ++v) {
            const float p = __builtin_amdgcn_exp2f(s[c][v] - mnew);
            s[c][v] = p;
            psum += p;
        }
    psum += __shfl_xor(psum, 16, 64);
    psum += __shfl_xor(psum, 32, 64);
    lsum = lsum * scale + psum;
    m = mnew;
    #pragma unroll
    for (int dkc = 0; dkc < 4; ++dkc) o[dkc] *= scale;

    // ---- P^T -> LDS [q][kv] (packed bf16 pairs, 4x ds_write_b64) ----
    #pragma unroll
    for (int c = 0; c < 4; ++c) {
        uint2 w;
        w.x = (unsigned int)f32_bf16(s[c][0]) | ((unsigned int)f32_bf16(s[c][1]) << 16);
        w.y = (unsigned int)f32_bf16(s[c][2]) | ((unsigned int)f32_bf16(s[c][3]) << 16);
        *reinterpret_cast<uint2*>(&Plds[l15][c*16 + l4*4]) = w;
    }
    // ---- B-frag read: P[kv][q], contiguous in kv for q = l15 ----
    s16x8 pb[2];
    #pragma unroll
    for (int ks = 0; ks < 2; ++ks)
        pb[ks] = *reinterpret_cast<const s16x8*>(&Plds[l15][ks*32 + l4*8]);

    // ---- O^T[dk][q] += V^T[dk][kv] @ P[kv][q] ----
    #pragma unroll
    for (int dkc = 0; dkc < 4; ++dkc)
        #pragma unroll
        for (int ks = 0; ks < 2; ++ks)
            o[dkc] = __builtin_amdgcn_mfma_f32_16x16x32_bf16(vf[dkc][ks], pb[ks], o[dkc], 0, 0, 0);
}

__device__ __forceinline__ void attn_tile(
    int qb, int l15, int l4, int h, int b,
    const unsigned short* __restrict__ Qp,
    const unsigned short* __restrict__ Kp,
    const unsigned short* __restrict__ Vp,
    unsigned short* __restrict__ Ctx,
    unsigned short (*Plds)[80])
{
    // Q fragments (B-operand of swapped QK^T): lane reads Q[qb+l15][k-slice]
    s16x8 qf[2];
    #pragma unroll
    for (int ks = 0; ks < 2; ++ks)
        qf[ks] = *reinterpret_cast<const s16x8*>(Qp + (size_t)(qb + l15) * HDIM + ks*32 + l4*8);

    f32x4 o[4] = {};
    float m = -1e30f, lsum = 0.0f;

    // full (unmasked) iterations: [0, full_end); then EXACTLY ONE masked iter.
    const int full_end = (qb >= 63) ? ((((qb - 63) >> 6) << 6) + 64) : 0;

    s16x8 kA[4][2], vA[4][2], kB[4][2], vB[4][2];
    load_kv(Kp, Vp, 0, l15, l4, kA, vA);
    bool useA = true;
    for (int kv0 = 0; kv0 < full_end; kv0 += 64) {
        if (useA) {
            load_kv(Kp, Vp, kv0 + 64, l15, l4, kB, vB);   // prefetch next (<= masked block, in-bounds)
            attn_compute<false>(kv0, qb, l15, l4, kA, vA, qf, o, m, lsum, Plds);
        } else {
            load_kv(Kp, Vp, kv0 + 64, l15, l4, kA, vA);
            attn_compute<false>(kv0, qb, l15, l4, kB, vB, qf, o, m, lsum, Plds);
        }
        useA = !useA;
    }
    if (useA) attn_compute<true>(full_end, qb, l15, l4, kA, vA, qf, o, m, lsum, Plds);
    else      attn_compute<true>(full_end, qb, l15, l4, kB, vB, qf, o, m, lsum, Plds);

    // ---- normalize + store ctx [B][S][NHEAD][DK] bf16 (q = l15) ----
    const float inv = 1.0f / lsum;
    unsigned short* cp = Ctx + (((size_t)b * S_LEN + qb + l15) * NHEAD + h) * HDIM;
    #pragma unroll
    for (int dkc = 0; dkc < 4; ++dkc) {
        ushort4 r;
        r.x = f32_bf16(o[dkc][0] * inv);
        r.y = f32_bf16(o[dkc][1] * inv);
        r.z = f32_bf16(o[dkc][2] * inv);
        r.w = f32_bf16(o[dkc][3] * inv);
        *reinterpret_cast<ushort4*>(cp + dkc*16 + l4*4) = r;
    }
}

__global__ __launch_bounds__(256, 2) void attn_k(
    const unsigned short* __restrict__ Q,
    const unsigned short* __restrict__ Kb,
    const unsigned short* __restrict__ Vt,
    unsigned short* __restrict__ Ctx)
{
    __shared__ unsigned short Plds[4][16][80];  // per-wave P tile [q16][kv64]

    const int tid  = threadIdx.x;
    const int lane = tid & 63;
    const int l15  = lane & 15;
    const int l4   = lane >> 4;
    const int wave = tid >> 6;

    const int t  = blockIdx.x;            // 0..15: handles q-tiles t and 31-t
    const int h  = blockIdx.y;
    const int b  = blockIdx.z;
    const int g  = h >> 2;                // kv head

    const unsigned short* Qp = Q  + ((size_t)b * NHEAD + h) * S_LEN * HDIM;
    const unsigned short* Kp = Kb + ((size_t)b * NKV  + g) * S_LEN * HDIM;
    const unsigned short* Vp = Vt + ((size_t)b * NKV  + g) * HDIM * S_LEN;

    const int NT = S_LEN / 64;            // 32 q-tiles of 64 rows

    attn_tile(t * 64 + wave * 16,            l15, l4, h, b, Qp, Kp, Vp, Ctx, Plds[wave]);
    attn_tile((NT - 1 - t) * 64 + wave * 16, l15, l4, h, b, Qp, Kp, Vp, Ctx, Plds[wave]);
}

// ---------------- launch ----------------
// ws layout (ushorts), Ctx aliases xb (dead after QKV GEMMs). Total ~23 MiB.
extern "C" void kernel_launch(void* const* d_in, const int* in_sizes, int n_in,
                              void* d_out, int out_size, void* d_ws, size_t ws_size,
                              hipStream_t stream) {
    const float* x  = (const float*)d_in[0];
    const float* wq = (const float*)d_in[1];
    const float* wk = (const float*)d_in[2];
    const float* wv = (const float*)d_in[3];
    const float* wo = (const float*)d_in[4];
    float* out = (float*)d_out;

    const int M = NBATCH * S_LEN;          // 4096
    const int nX  = M * DMODEL;            // 4194304
    const int nWq = DMODEL * NHEAD * HDIM; // 1048576
    const int nWk = DMODEL * NKV * HDIM;   // 262144
    const int nWo = DMODEL * DMODEL;       // 1048576
    const int nQ  = NBATCH * NHEAD * S_LEN * HDIM;  // 4194304
    const int nKV = NBATCH * NKV * S_LEN * HDIM;    // 1048576

    unsigned short* xb  = (unsigned short*)d_ws;
    unsigned short* wqb = xb  + nX;
    unsigned short* wkb = wqb + nWq;
    unsigned short* wvb = wkb + nWk;
    unsigned short* wob = wvb + nWk;
    unsigned short* Qb  = wob + nWo;
    unsigned short* Kb  = Qb  + nQ;
    unsigned short* Vbuf= Kb  + nKV;
    unsigned short* Ctx = xb;              // alias: xb dead after QKV GEMMs

    cvt_bf16_k<<<nX  / 1024, 256, 0, stream>>>(x,  xb,  nX  / 4);
    cvt_bf16_k<<<nWq / 1024, 256, 0, stream>>>(wq, wqb, nWq / 4);
    cvt_bf16_k<<<nWk / 1024, 256, 0, stream>>>(wk, wkb, nWk / 4);
    cvt_bf16_k<<<nWk / 1024, 256, 0, stream>>>(wv, wvb, nWk / 4);
    cvt_bf16_k<<<nWo / 1024, 256, 0, stream>>>(wo, wob, nWo / 4);

    // Q: rope + QSCALE (exp2-domain softmax). K: rope only. V: transposed store.
    gemm_k<1><<<dim3((NHEAD*HDIM)/64, M/64), 256, 0, stream>>>(xb, wqb, Qb,   NHEAD*HDIM, DMODEL, NHEAD, QSCALE);
    gemm_k<1><<<dim3((NKV*HDIM)/64,  M/64), 256, 0, stream>>>(xb, wkb, Kb,   NKV*HDIM,  DMODEL, NKV,  1.0f);
    gemm_k<3><<<dim3((NKV*HDIM)/64,  M/64), 256, 0, stream>>>(xb, wvb, Vbuf, NKV*HDIM,  DMODEL, NKV,  1.0f);

    attn_k<<<dim3(S_LEN/128, NHEAD, NBATCH), 256, 0, stream>>>(Qb, Kb, Vbuf, Ctx);

    gemm_k<0><<<dim3(DMODEL/64, M/64), 256, 0, stream>>>(Ctx, wob, out, DMODEL, DMODEL, 0, 1.0f);
}

// Round 6
// 237.829 us; speedup vs baseline: 1.6556x; 1.6556x over previous
//
#include <hip/hip_runtime.h>
#include <hip/hip_bf16.h>

#define S_LEN 2048
#define NBATCH 2
#define DMODEL 1024
#define NHEAD 16
#define NKV 4
#define HDIM 64

typedef __attribute__((ext_vector_type(4))) float f32x4;
typedef __attribute__((ext_vector_type(8))) short s16x8;

// 0.125 (1/sqrt(dk)) * log2(e): Q pre-scale so softmax runs in exp2 domain
#define QSCALE 0.18033688011112042f

__device__ __forceinline__ unsigned short f32_bf16(float f) {
    unsigned int u = __float_as_uint(f);
    u += 0x7FFFu + ((u >> 16) & 1u);
    return (unsigned short)(u >> 16);
}

// ---------------- f32 -> bf16 convert ----------------
__global__ __launch_bounds__(256) void cvt_bf16_k(const float* __restrict__ in,
                                                  unsigned short* __restrict__ out, int n4) {
    int i = blockIdx.x * 256 + threadIdx.x;
    if (i < n4) {
        const float4 v = reinterpret_cast<const float4*>(in)[i];
        ushort4 r;
        r.x = f32_bf16(v.x); r.y = f32_bf16(v.y);
        r.z = f32_bf16(v.z); r.w = f32_bf16(v.w);
        reinterpret_cast<ushort4*>(out)[i] = r;
    }
}

// ---------------- GEMM: C[M][N] = A[M][K] @ W[K][N], bf16 in, f32 acc ----------------
// EPI 0: f32 row-major out.
// EPI 1: rope + *oscale + bf16 head-layout [B][nheads][S][DK].
// EPI 3: bf16 TRANSPOSED head-layout [B][nheads][DK][S]  (for V)
template<int EPI>
__global__ __launch_bounds__(256) void gemm_k(
    const unsigned short* __restrict__ A,
    const unsigned short* __restrict__ W,
    void* __restrict__ Out, int N, int K, int nheads, float oscale)
{
    __shared__ unsigned short As[64][72];   // [m][k], +8 pad
    __shared__ unsigned short Bs[64][72];   // [n][k] (transposed), +8 pad

    const int tid  = threadIdx.x;
    const int lane = tid & 63;
    const int l15  = lane & 15;
    const int l4   = lane >> 4;
    const int wave = tid >> 6;
    const int wr   = (wave >> 1) * 32;
    const int wc   = (wave & 1) * 32;
    const int bm   = blockIdx.y * 64;
    const int bn   = blockIdx.x * 64;

    f32x4 acc[2][2] = {};

    for (int k0 = 0; k0 < K; k0 += 64) {
        #pragma unroll
        for (int cc = 0; cc < 2; ++cc) {
            const int c   = tid + cc * 256;      // 512 chunks of 8 elems
            const int row = c >> 3;
            const int col = (c & 7) * 8;
            *reinterpret_cast<s16x8*>(&As[row][col]) =
                *reinterpret_cast<const s16x8*>(A + (size_t)(bm + row) * K + k0 + col);
            const s16x8 wv =
                *reinterpret_cast<const s16x8*>(W + (size_t)(k0 + row) * N + bn + col);
            #pragma unroll
            for (int i = 0; i < 8; ++i) Bs[col + i][row] = (short)wv[i];
        }
        __syncthreads();
        #pragma unroll
        for (int ks = 0; ks < 2; ++ks) {
            s16x8 af[2], bfv[2];
            #pragma unroll
            for (int i = 0; i < 2; ++i)
                af[i] = *reinterpret_cast<const s16x8*>(&As[wr + i*16 + l15][ks*32 + l4*8]);
            #pragma unroll
            for (int j = 0; j < 2; ++j)
                bfv[j] = *reinterpret_cast<const s16x8*>(&Bs[wc + j*16 + l15][ks*32 + l4*8]);
            #pragma unroll
            for (int i = 0; i < 2; ++i)
                #pragma unroll
                for (int j = 0; j < 2; ++j)
                    acc[i][j] = __builtin_amdgcn_mfma_f32_16x16x32_bf16(
                        af[i], bfv[j], acc[i][j], 0, 0, 0);
        }
        __syncthreads();
    }

    #pragma unroll
    for (int i = 0; i < 2; ++i) {
        #pragma unroll
        for (int j = 0; j < 2; ++j) {
            #pragma unroll
            for (int v = 0; v < 4; ++v) {
                const int gr = bm + wr + i*16 + l4*4 + v;
                const int gc = bn + wc + j*16 + l15;
                float val = acc[i][j][v];
                if (EPI == 0) {
                    reinterpret_cast<float*>(Out)[(size_t)gr * N + gc] = val;
                } else {
                    if (EPI == 1) {
                        const float partner = __shfl_xor(val, 1, 64);
                        const int   jp = (gc & 63) >> 1;      // pair index 0..31
                        const int   hh = gc >> 6;             // head index
                        // inv_freq = 10000^(-2*jp/64)
                        const float inv = __expf((float)jp * (-2.0f / 64.0f) * 9.210340371976184f);
                        const float ang = (float)hh * inv;
                        float sn, cs;
                        __sincosf(ang, &sn, &cs);
                        val = ((gc & 1) == 0) ? (val * cs - partner * sn)
                                              : (partner * sn + val * cs);
                        val *= oscale;
                    }
                    const int b  = gr >> 11;       // / S_LEN
                    const int sr = gr & (S_LEN - 1);
                    const int hh = gc >> 6;
                    const int dk = gc & 63;
                    if (EPI == 3) {
                        reinterpret_cast<unsigned short*>(Out)[
                            (((size_t)b * nheads + hh) * HDIM + dk) * S_LEN + sr] = f32_bf16(val);
                    } else {
                        reinterpret_cast<unsigned short*>(Out)[
                            (((size_t)b * nheads + hh) * S_LEN + sr) * HDIM + dk] = f32_bf16(val);
                    }
                }
            }
        }
    }
}

// ---------------- flash attention (causal, GQA), LDS-staged K/V ----------------
// Q: [B][NHEAD][S][DK] bf16 (rope+QSCALE applied), K: [B][NKV][S][DK],
// Vt: [B][NKV][DK][S] (transposed), Ctx out: [B][S][NHEAD][DK] bf16.
// Block = 4 waves over one 64-row q-tile; all waves share K/V tiles staged
// in LDS (4x dedup), double-buffered: loads for tile t+1 issue BEFORE the
// compute of tile t, ds_write after (T14 async-split), one barrier per tile.
// Every wave runs nt tiles; only the diagonal tile is masked (uniform flow).

__device__ __forceinline__ void stage_load(
    const unsigned short* __restrict__ Kp,
    const unsigned short* __restrict__ Vp,
    int kv0, int tid, s16x8 (&kr)[2], s16x8 (&vr)[2])
{
    #pragma unroll
    for (int cc = 0; cc < 2; ++cc) {
        const int c = cc * 256 + tid;       // 512 chunks of 16B per tile
        const int r = c >> 3, col = (c & 7) * 8;
        kr[cc] = *reinterpret_cast<const s16x8*>(Kp + (size_t)(kv0 + r) * HDIM + col);
        vr[cc] = *reinterpret_cast<const s16x8*>(Vp + (size_t)r * S_LEN + kv0 + col);
    }
}

__device__ __forceinline__ void stage_write(
    unsigned short (*Ksb)[72], unsigned short (*Vsb)[72],
    int tid, const s16x8 (&kr)[2], const s16x8 (&vr)[2])
{
    #pragma unroll
    for (int cc = 0; cc < 2; ++cc) {
        const int c = cc * 256 + tid;
        const int r = c >> 3, col = (c & 7) * 8;
        *reinterpret_cast<s16x8*>(&Ksb[r][col]) = kr[cc];
        *reinterpret_cast<s16x8*>(&Vsb[r][col]) = vr[cc];
    }
}

template<bool MASK>
__device__ __forceinline__ void attn_compute(
    int l15, int l4, int wave,
    const unsigned short (*Ksb)[72], const unsigned short (*Vsb)[72],
    const s16x8 qf[2], f32x4 o[4], float& m, float& lsum,
    unsigned short (*Plds)[72])
{
    // ---- S^T[kv][q] = K @ Q^T: lane holds kv = c*16 + l4*4 + v for q = l15 ----
    f32x4 s[4] = {};
    #pragma unroll
    for (int c = 0; c < 4; ++c)
        #pragma unroll
        for (int ks = 0; ks < 2; ++ks) {
            const s16x8 kf = *reinterpret_cast<const s16x8*>(&Ksb[c*16 + l15][ks*32 + l4*8]);
            s[c] = __builtin_amdgcn_mfma_f32_16x16x32_bf16(kf, qf[ks], s[c], 0, 0, 0);
        }

    if (MASK) {
        const int qloc = wave*16 + l15;     // q, kv relative to same tile base
        #pragma unroll
        for (int c = 0; c < 4; ++c)
            #pragma unroll
            for (int v = 0; v < 4; ++v) {
                const int kvloc = c*16 + l4*4 + v;
                s[c][v] = (kvloc <= qloc) ? s[c][v] : -1e30f;
            }
    }

    // ---- online softmax, lane-local + 2-shuffle cross-group reduce ----
    float mx = -1e30f;
    #pragma unroll
    for (int c = 0; c < 4; ++c)
        #pragma unroll
        for (int v = 0; v < 4; ++v) mx = fmaxf(mx, s[c][v]);
    mx = fmaxf(mx, __shfl_xor(mx, 16, 64));
    mx = fmaxf(mx, __shfl_xor(mx, 32, 64));
    const float mnew  = fmaxf(m, mx);
    const float scale = __builtin_amdgcn_exp2f(m - mnew);
    float psum = 0.0f;
    #pragma unroll
    for (int c = 0; c < 4; ++c)
        #pragma unroll
        for (int v = 0; v < 4; ++v) {
            const float p = __builtin_amdgcn_exp2f(s[c][v] - mnew);
            s[c][v] = p;
            psum += p;
        }
    psum += __shfl_xor(psum, 16, 64);
    psum += __shfl_xor(psum, 32, 64);
    lsum = lsum * scale + psum;
    m = mnew;
    #pragma unroll
    for (int dkc = 0; dkc < 4; ++dkc) o[dkc] *= scale;

    // ---- P -> per-wave LDS [q][kv] (packed bf16 pairs), read back as B-frag ----
    #pragma unroll
    for (int c = 0; c < 4; ++c) {
        uint2 w;
        w.x = (unsigned int)f32_bf16(s[c][0]) | ((unsigned int)f32_bf16(s[c][1]) << 16);
        w.y = (unsigned int)f32_bf16(s[c][2]) | ((unsigned int)f32_bf16(s[c][3]) << 16);
        *reinterpret_cast<uint2*>(&Plds[l15][c*16 + l4*4]) = w;
    }
    s16x8 pb[2];
    #pragma unroll
    for (int ks = 0; ks < 2; ++ks)
        pb[ks] = *reinterpret_cast<const s16x8*>(&Plds[l15][ks*32 + l4*8]);

    // ---- O^T[dk][q] += V^T[dk][kv] @ P[kv][q] ----
    #pragma unroll
    for (int dkc = 0; dkc < 4; ++dkc)
        #pragma unroll
        for (int ks = 0; ks < 2; ++ks) {
            const s16x8 vf = *reinterpret_cast<const s16x8*>(&Vsb[dkc*16 + l15][ks*32 + l4*8]);
            o[dkc] = __builtin_amdgcn_mfma_f32_16x16x32_bf16(vf, pb[ks], o[dkc], 0, 0, 0);
        }
}

__global__ __launch_bounds__(256, 3) void attn_k(
    const unsigned short* __restrict__ Q,
    const unsigned short* __restrict__ Kb,
    const unsigned short* __restrict__ Vt,
    unsigned short* __restrict__ Ctx)
{
    __shared__ unsigned short Ks[2][64][72];    // K tile double-buffer [kv][dk]
    __shared__ unsigned short Vs[2][64][72];    // V^T tile double-buffer [dk][kv]
    __shared__ unsigned short Plds[4][16][72];  // per-wave P tile [q16][kv64]

    const int tid  = threadIdx.x;
    const int lane = tid & 63;
    const int l15  = lane & 15;
    const int l4   = lane >> 4;
    const int wave = tid >> 6;

    // reversed order: biggest causal blocks launch first (LPT)
    const int qb0 = (gridDim.x - 1 - blockIdx.x) * 64;
    const int h   = blockIdx.y;
    const int b   = blockIdx.z;
    const int g   = h >> 2;   // kv head

    const unsigned short* Qp = Q  + ((size_t)b * NHEAD + h) * S_LEN * HDIM;
    const unsigned short* Kp = Kb + ((size_t)b * NKV  + g) * S_LEN * HDIM;
    const unsigned short* Vp = Vt + ((size_t)b * NKV  + g) * HDIM * S_LEN;

    const int qb = qb0 + wave * 16;   // this wave's 16 q-rows

    // Q fragments (B-operand of swapped QK^T)
    s16x8 qf[2];
    #pragma unroll
    for (int ks = 0; ks < 2; ++ks)
        qf[ks] = *reinterpret_cast<const s16x8*>(Qp + (size_t)(qb + l15) * HDIM + ks*32 + l4*8);

    f32x4 o[4] = {};
    float m = -1e30f, lsum = 0.0f;

    const int nt = (qb0 >> 6) + 1;   // kv tiles; last one is the masked diagonal

    // prologue: tile 0 -> buf 0
    {
        s16x8 kr[2], vr[2];
        stage_load(Kp, Vp, 0, tid, kr, vr);
        stage_write(Ks[0], Vs[0], tid, kr, vr);
        __syncthreads();
    }

    // full (unmasked) tiles, each prefetching the next
    for (int t = 0; t < nt - 1; ++t) {
        const int cur = t & 1;
        s16x8 kr[2], vr[2];
        stage_load(Kp, Vp, (t + 1) * 64, tid, kr, vr);            // issue early
        attn_compute<false>(l15, l4, wave, Ks[cur], Vs[cur], qf, o, m, lsum, Plds[wave]);
        stage_write(Ks[cur ^ 1], Vs[cur ^ 1], tid, kr, vr);       // waits vmcnt here
        __syncthreads();
    }
    // diagonal (masked) tile
    attn_compute<true>(l15, l4, wave, Ks[(nt - 1) & 1], Vs[(nt - 1) & 1],
                       qf, o, m, lsum, Plds[wave]);

    // ---- normalize + store ctx [B][S][NHEAD][DK] bf16 (q = l15) ----
    const float inv = 1.0f / lsum;
    unsigned short* cp = Ctx + (((size_t)b * S_LEN + qb + l15) * NHEAD + h) * HDIM;
    #pragma unroll
    for (int dkc = 0; dkc < 4; ++dkc) {
        ushort4 r;
        r.x = f32_bf16(o[dkc][0] * inv);
        r.y = f32_bf16(o[dkc][1] * inv);
        r.z = f32_bf16(o[dkc][2] * inv);
        r.w = f32_bf16(o[dkc][3] * inv);
        *reinterpret_cast<ushort4*>(cp + dkc*16 + l4*4) = r;
    }
}

// ---------------- launch ----------------
// ws layout (ushorts), Ctx aliases xb (dead after QKV GEMMs). Total ~23 MiB.
extern "C" void kernel_launch(void* const* d_in, const int* in_sizes, int n_in,
                              void* d_out, int out_size, void* d_ws, size_t ws_size,
                              hipStream_t stream) {
    const float* x  = (const float*)d_in[0];
    const float* wq = (const float*)d_in[1];
    const float* wk = (const float*)d_in[2];
    const float* wv = (const float*)d_in[3];
    const float* wo = (const float*)d_in[4];
    float* out = (float*)d_out;

    const int M = NBATCH * S_LEN;          // 4096
    const int nX  = M * DMODEL;            // 4194304
    const int nWq = DMODEL * NHEAD * HDIM; // 1048576
    const int nWk = DMODEL * NKV * HDIM;   // 262144
    const int nWo = DMODEL * DMODEL;       // 1048576
    const int nQ  = NBATCH * NHEAD * S_LEN * HDIM;  // 4194304
    const int nKV = NBATCH * NKV * S_LEN * HDIM;    // 1048576

    unsigned short* xb  = (unsigned short*)d_ws;
    unsigned short* wqb = xb  + nX;
    unsigned short* wkb = wqb + nWq;
    unsigned short* wvb = wkb + nWk;
    unsigned short* wob = wvb + nWk;
    unsigned short* Qb  = wob + nWo;
    unsigned short* Kb  = Qb  + nQ;
    unsigned short* Vbuf= Kb  + nKV;
    unsigned short* Ctx = xb;              // alias: xb dead after QKV GEMMs

    cvt_bf16_k<<<nX  / 1024, 256, 0, stream>>>(x,  xb,  nX  / 4);
    cvt_bf16_k<<<nWq / 1024, 256, 0, stream>>>(wq, wqb, nWq / 4);
    cvt_bf16_k<<<nWk / 1024, 256, 0, stream>>>(wk, wkb, nWk / 4);
    cvt_bf16_k<<<nWk / 1024, 256, 0, stream>>>(wv, wvb, nWk / 4);
    cvt_bf16_k<<<nWo / 1024, 256, 0, stream>>>(wo, wob, nWo / 4);

    // Q: rope + QSCALE (exp2-domain softmax). K: rope only. V: transposed store.
    gemm_k<1><<<dim3((NHEAD*HDIM)/64, M/64), 256, 0, stream>>>(xb, wqb, Qb,   NHEAD*HDIM, DMODEL, NHEAD, QSCALE);
    gemm_k<1><<<dim3((NKV*HDIM)/64,  M/64), 256, 0, stream>>>(xb, wkb, Kb,   NKV*HDIM,  DMODEL, NKV,  1.0f);
    gemm_k<3><<<dim3((NKV*HDIM)/64,  M/64), 256, 0, stream>>>(xb, wvb, Vbuf, NKV*HDIM,  DMODEL, NKV,  1.0f);

    attn_k<<<dim3(S_LEN/64, NHEAD, NBATCH), 256, 0, stream>>>(Qb, Kb, Vbuf, Ctx);

    gemm_k<0><<<dim3(DMODEL/64, M/64), 256, 0, stream>>>(Ctx, wob, out, DMODEL, DMODEL, 0, 1.0f);
}

// Round 7
// 138.345 us; speedup vs baseline: 2.8461x; 1.7191x over previous
//
#include <hip/hip_runtime.h>
#include <hip/hip_bf16.h>

#define S_LEN 2048
#define NBATCH 2
#define DMODEL 1024
#define NHEAD 16
#define NKV 4
#define HDIM 64

typedef __attribute__((ext_vector_type(4))) float f32x4;
typedef __attribute__((ext_vector_type(8))) short s16x8;

// 0.125 (1/sqrt(dk)) * log2(e): Q pre-scale so softmax runs in exp2 domain
#define QSCALE 0.18033688011112042f

__device__ __forceinline__ unsigned short f32_bf16(float f) {
    unsigned int u = __float_as_uint(f);
    u += 0x7FFFu + ((u >> 16) & 1u);
    return (unsigned short)(u >> 16);
}

// ---------------- f32 -> bf16 convert (x) ----------------
__global__ __launch_bounds__(256) void cvt_bf16_k(const float* __restrict__ in,
                                                  unsigned short* __restrict__ out, int n4) {
    int i = blockIdx.x * 256 + threadIdx.x;
    if (i < n4) {
        const float4 v = reinterpret_cast<const float4*>(in)[i];
        ushort4 r;
        r.x = f32_bf16(v.x); r.y = f32_bf16(v.y);
        r.z = f32_bf16(v.z); r.w = f32_bf16(v.w);
        reinterpret_cast<ushort4*>(out)[i] = r;
    }
}

// ---------------- f32 -> bf16 convert + TRANSPOSE (weights) ----------------
// in: f32 [1024][N] row-major; out rows [n_off + n][k] of a bf16 [*][1024] buffer.
__global__ __launch_bounds__(256) void cvtT_k(const float* __restrict__ in,
                                              unsigned short* __restrict__ out,
                                              int N, int n_off) {
    __shared__ float t[64][65];
    const int n0  = blockIdx.x * 64;
    const int k0  = blockIdx.y * 64;
    const int tid = threadIdx.x;
    const int r   = tid >> 4;          // 0..15
    const int c4  = (tid & 15) * 4;    // 0..60
    #pragma unroll
    for (int i = 0; i < 4; ++i) {
        const float4 v = *reinterpret_cast<const float4*>(
            in + (size_t)(k0 + i*16 + r) * N + n0 + c4);
        t[i*16 + r][c4+0] = v.x; t[i*16 + r][c4+1] = v.y;
        t[i*16 + r][c4+2] = v.z; t[i*16 + r][c4+3] = v.w;
    }
    __syncthreads();
    #pragma unroll
    for (int i = 0; i < 4; ++i) {
        const int n = i*16 + r;
        ushort4 o;
        o.x = f32_bf16(t[c4+0][n]); o.y = f32_bf16(t[c4+1][n]);
        o.z = f32_bf16(t[c4+2][n]); o.w = f32_bf16(t[c4+3][n]);
        *reinterpret_cast<ushort4*>(out + (size_t)(n_off + n0 + n) * 1024 + k0 + c4) = o;
    }
}

// ---------------- GEMM2: C[M][N] = A[M][K] @ Bt[N][K]^T, bf16, f32 acc ----------------
// 128M x 64N tile, BK=64, double-buffered LDS, XOR-swizzled (slot^(r&7)) on
// both write and read sides (reg-staged). EPI 0: f32 row-major out.
// EPI 1: fused QKV epilogue — block-uniform branch on bn:
//   bn < 1024: Q rope(head gc>>6) * QSCALE -> Qb head-layout
//   bn < 1280: K rope(head (gc-1024)>>6)   -> Kbuf head-layout
//   else     : V                            -> Vbuf TRANSPOSED [dk][s]
template<int EPI>
__global__ __launch_bounds__(256, 2) void gemm2_k(
    const unsigned short* __restrict__ A,
    const unsigned short* __restrict__ Bt,
    int N, int K,
    float* __restrict__ OutF,
    unsigned short* __restrict__ Qb,
    unsigned short* __restrict__ Kbuf,
    unsigned short* __restrict__ Vbuf)
{
    __shared__ unsigned short As[2][128 * 64];
    __shared__ unsigned short Bs[2][64 * 64];

    const int tid  = threadIdx.x;
    const int lane = tid & 63;
    const int l15  = lane & 15;
    const int l4   = lane >> 4;
    const int wave = tid >> 6;
    const int wm   = wave >> 1;      // 0-1: 64-row half
    const int wn   = wave & 1;       // 0-1: 32-col half
    const int bm   = blockIdx.y * 128;
    const int bn   = blockIdx.x * 64;

    f32x4 acc[4][2] = {};
    s16x8 ar[4], br[2];

    const int NT = K >> 6;

    // ---- staging helpers: chunk c -> row c>>3, slot c&7; LDS slot = s^(r&7) ----
    #define GLOAD(k0)                                                              \
        {                                                                          \
            _Pragma("unroll")                                                      \
            for (int p = 0; p < 4; ++p) {                                          \
                const int c = p*256 + tid, r_ = c >> 3, s_ = c & 7;                \
                ar[p] = *reinterpret_cast<const s16x8*>(                           \
                    A + (size_t)(bm + r_) * K + (k0) + s_*8);                      \
            }                                                                      \
            _Pragma("unroll")                                                      \
            for (int p = 0; p < 2; ++p) {                                          \
                const int c = p*256 + tid, r_ = c >> 3, s_ = c & 7;                \
                br[p] = *reinterpret_cast<const s16x8*>(                           \
                    Bt + (size_t)(bn + r_) * K + (k0) + s_*8);                     \
            }                                                                      \
        }
    #define LWRITE(buf)                                                            \
        {                                                                          \
            _Pragma("unroll")                                                      \
            for (int p = 0; p < 4; ++p) {                                          \
                const int c = p*256 + tid, r_ = c >> 3, s_ = c & 7;                \
                *reinterpret_cast<s16x8*>(                                         \
                    &As[buf][r_*64 + ((s_ ^ (r_ & 7)) * 8)]) = ar[p];              \
            }                                                                      \
            _Pragma("unroll")                                                      \
            for (int p = 0; p < 2; ++p) {                                          \
                const int c = p*256 + tid, r_ = c >> 3, s_ = c & 7;                \
                *reinterpret_cast<s16x8*>(                                         \
                    &Bs[buf][r_*64 + ((s_ ^ (r_ & 7)) * 8)]) = br[p];              \
            }                                                                      \
        }

    GLOAD(0); LWRITE(0); __syncthreads();

    for (int kt = 0; kt < NT; ++kt) {
        const int cur = kt & 1;
        if (kt + 1 < NT) GLOAD((kt + 1) << 6);          // issue next tile early
        #pragma unroll
        for (int ks = 0; ks < 2; ++ks) {
            s16x8 af[4], bfv[2];
            #pragma unroll
            for (int mi = 0; mi < 4; ++mi) {
                const int r = wm*64 + mi*16 + l15;
                af[mi] = *reinterpret_cast<const s16x8*>(
                    &As[cur][r*64 + (((ks*4 + l4) ^ (r & 7)) * 8)]);
            }
            #pragma unroll
            for (int nj = 0; nj < 2; ++nj) {
                const int r = wn*32 + nj*16 + l15;
                bfv[nj] = *reinterpret_cast<const s16x8*>(
                    &Bs[cur][r*64 + (((ks*4 + l4) ^ (r & 7)) * 8)]);
            }
            #pragma unroll
            for (int mi = 0; mi < 4; ++mi)
                #pragma unroll
                for (int nj = 0; nj < 2; ++nj)
                    acc[mi][nj] = __builtin_amdgcn_mfma_f32_16x16x32_bf16(
                        af[mi], bfv[nj], acc[mi][nj], 0, 0, 0);
        }
        if (kt + 1 < NT) LWRITE(cur ^ 1);               // vmcnt waits here (T14)
        __syncthreads();
    }
    #undef GLOAD
    #undef LWRITE

    // ---- epilogue ----
    #pragma unroll
    for (int mi = 0; mi < 4; ++mi) {
        #pragma unroll
        for (int nj = 0; nj < 2; ++nj) {
            #pragma unroll
            for (int v = 0; v < 4; ++v) {
                const int gr = bm + wm*64 + mi*16 + l4*4 + v;
                const int gc = bn + wn*32 + nj*16 + l15;
                float val = acc[mi][nj][v];
                if (EPI == 0) {
                    OutF[(size_t)gr * N + gc] = val;
                } else {
                    const int b  = gr >> 11;           // / S_LEN
                    const int sr = gr & (S_LEN - 1);
                    const int dk = gc & 63;
                    if (bn < 1024) {                   // Q: rope + QSCALE
                        const float partner = __shfl_xor(val, 1, 64);
                        const int   jp  = dk >> 1;
                        const float inv = __expf((float)jp * (-2.0f / 64.0f) * 9.210340371976184f);
                        const int   hh  = gc >> 6;
                        float sn, cs;
                        __sincosf((float)hh * inv, &sn, &cs);
                        val = ((gc & 1) == 0) ? (val * cs - partner * sn)
                                              : (partner * sn + val * cs);
                        val *= QSCALE;
                        Qb[(((size_t)b * NHEAD + hh) * S_LEN + sr) * HDIM + dk] = f32_bf16(val);
                    } else if (bn < 1280) {            // K: rope (kv-head index)
                        const float partner = __shfl_xor(val, 1, 64);
                        const int   jp  = dk >> 1;
                        const float inv = __expf((float)jp * (-2.0f / 64.0f) * 9.210340371976184f);
                        const int   hh  = (gc - 1024) >> 6;
                        float sn, cs;
                        __sincosf((float)hh * inv, &sn, &cs);
                        val = ((gc & 1) == 0) ? (val * cs - partner * sn)
                                              : (partner * sn + val * cs);
                        Kbuf[(((size_t)b * NKV + hh) * S_LEN + sr) * HDIM + dk] = f32_bf16(val);
                    } else {                           // V: transposed [dk][s]
                        const int hh = (gc - 1280) >> 6;
                        Vbuf[(((size_t)b * NKV + hh) * HDIM + dk) * S_LEN + sr] = f32_bf16(val);
                    }
                }
            }
        }
    }
}

// ---------------- flash attention (causal, GQA), LDS-staged K/V ----------------
// (unchanged from R6 — 84 us, verified)
__device__ __forceinline__ void stage_load(
    const unsigned short* __restrict__ Kp,
    const unsigned short* __restrict__ Vp,
    int kv0, int tid, s16x8 (&kr)[2], s16x8 (&vr)[2])
{
    #pragma unroll
    for (int cc = 0; cc < 2; ++cc) {
        const int c = cc * 256 + tid;       // 512 chunks of 16B per tile
        const int r = c >> 3, col = (c & 7) * 8;
        kr[cc] = *reinterpret_cast<const s16x8*>(Kp + (size_t)(kv0 + r) * HDIM + col);
        vr[cc] = *reinterpret_cast<const s16x8*>(Vp + (size_t)r * S_LEN + kv0 + col);
    }
}

__device__ __forceinline__ void stage_write(
    unsigned short (*Ksb)[72], unsigned short (*Vsb)[72],
    int tid, const s16x8 (&kr)[2], const s16x8 (&vr)[2])
{
    #pragma unroll
    for (int cc = 0; cc < 2; ++cc) {
        const int c = cc * 256 + tid;
        const int r = c >> 3, col = (c & 7) * 8;
        *reinterpret_cast<s16x8*>(&Ksb[r][col]) = kr[cc];
        *reinterpret_cast<s16x8*>(&Vsb[r][col]) = vr[cc];
    }
}

template<bool MASK>
__device__ __forceinline__ void attn_compute(
    int l15, int l4, int wave,
    const unsigned short (*Ksb)[72], const unsigned short (*Vsb)[72],
    const s16x8 qf[2], f32x4 o[4], float& m, float& lsum,
    unsigned short (*Plds)[72])
{
    f32x4 s[4] = {};
    #pragma unroll
    for (int c = 0; c < 4; ++c)
        #pragma unroll
        for (int ks = 0; ks < 2; ++ks) {
            const s16x8 kf = *reinterpret_cast<const s16x8*>(&Ksb[c*16 + l15][ks*32 + l4*8]);
            s[c] = __builtin_amdgcn_mfma_f32_16x16x32_bf16(kf, qf[ks], s[c], 0, 0, 0);
        }

    if (MASK) {
        const int qloc = wave*16 + l15;
        #pragma unroll
        for (int c = 0; c < 4; ++c)
            #pragma unroll
            for (int v = 0; v < 4; ++v) {
                const int kvloc = c*16 + l4*4 + v;
                s[c][v] = (kvloc <= qloc) ? s[c][v] : -1e30f;
            }
    }

    float mx = -1e30f;
    #pragma unroll
    for (int c = 0; c < 4; ++c)
        #pragma unroll
        for (int v = 0; v < 4; ++v) mx = fmaxf(mx, s[c][v]);
    mx = fmaxf(mx, __shfl_xor(mx, 16, 64));
    mx = fmaxf(mx, __shfl_xor(mx, 32, 64));
    const float mnew  = fmaxf(m, mx);
    const float scale = __builtin_amdgcn_exp2f(m - mnew);
    float psum = 0.0f;
    #pragma unroll
    for (int c = 0; c < 4; ++c)
        #pragma unroll
        for (int v = 0; v < 4; ++v) {
            const float p = __builtin_amdgcn_exp2f(s[c][v] - mnew);
            s[c][v] = p;
            psum += p;
        }
    psum += __shfl_xor(psum, 16, 64);
    psum += __shfl_xor(psum, 32, 64);
    lsum = lsum * scale + psum;
    m = mnew;
    #pragma unroll
    for (int dkc = 0; dkc < 4; ++dkc) o[dkc] *= scale;

    #pragma unroll
    for (int c = 0; c < 4; ++c) {
        uint2 w;
        w.x = (unsigned int)f32_bf16(s[c][0]) | ((unsigned int)f32_bf16(s[c][1]) << 16);
        w.y = (unsigned int)f32_bf16(s[c][2]) | ((unsigned int)f32_bf16(s[c][3]) << 16);
        *reinterpret_cast<uint2*>(&Plds[l15][c*16 + l4*4]) = w;
    }
    s16x8 pb[2];
    #pragma unroll
    for (int ks = 0; ks < 2; ++ks)
        pb[ks] = *reinterpret_cast<const s16x8*>(&Plds[l15][ks*32 + l4*8]);

    #pragma unroll
    for (int dkc = 0; dkc < 4; ++dkc)
        #pragma unroll
        for (int ks = 0; ks < 2; ++ks) {
            const s16x8 vf = *reinterpret_cast<const s16x8*>(&Vsb[dkc*16 + l15][ks*32 + l4*8]);
            o[dkc] = __builtin_amdgcn_mfma_f32_16x16x32_bf16(vf, pb[ks], o[dkc], 0, 0, 0);
        }
}

__global__ __launch_bounds__(256, 3) void attn_k(
    const unsigned short* __restrict__ Q,
    const unsigned short* __restrict__ Kb,
    const unsigned short* __restrict__ Vt,
    unsigned short* __restrict__ Ctx)
{
    __shared__ unsigned short Ks[2][64][72];
    __shared__ unsigned short Vs[2][64][72];
    __shared__ unsigned short Plds[4][16][72];

    const int tid  = threadIdx.x;
    const int lane = tid & 63;
    const int l15  = lane & 15;
    const int l4   = lane >> 4;
    const int wave = tid >> 6;

    const int qb0 = (gridDim.x - 1 - blockIdx.x) * 64;
    const int h   = blockIdx.y;
    const int b   = blockIdx.z;
    const int g   = h >> 2;

    const unsigned short* Qp = Q  + ((size_t)b * NHEAD + h) * S_LEN * HDIM;
    const unsigned short* Kp = Kb + ((size_t)b * NKV  + g) * S_LEN * HDIM;
    const unsigned short* Vp = Vt + ((size_t)b * NKV  + g) * HDIM * S_LEN;

    const int qb = qb0 + wave * 16;

    s16x8 qf[2];
    #pragma unroll
    for (int ks = 0; ks < 2; ++ks)
        qf[ks] = *reinterpret_cast<const s16x8*>(Qp + (size_t)(qb + l15) * HDIM + ks*32 + l4*8);

    f32x4 o[4] = {};
    float m = -1e30f, lsum = 0.0f;

    const int nt = (qb0 >> 6) + 1;

    {
        s16x8 kr[2], vr[2];
        stage_load(Kp, Vp, 0, tid, kr, vr);
        stage_write(Ks[0], Vs[0], tid, kr, vr);
        __syncthreads();
    }

    for (int t = 0; t < nt - 1; ++t) {
        const int cur = t & 1;
        s16x8 kr[2], vr[2];
        stage_load(Kp, Vp, (t + 1) * 64, tid, kr, vr);
        attn_compute<false>(l15, l4, wave, Ks[cur], Vs[cur], qf, o, m, lsum, Plds[wave]);
        stage_write(Ks[cur ^ 1], Vs[cur ^ 1], tid, kr, vr);
        __syncthreads();
    }
    attn_compute<true>(l15, l4, wave, Ks[(nt - 1) & 1], Vs[(nt - 1) & 1],
                       qf, o, m, lsum, Plds[wave]);

    const float inv = 1.0f / lsum;
    unsigned short* cp = Ctx + (((size_t)b * S_LEN + qb + l15) * NHEAD + h) * HDIM;
    #pragma unroll
    for (int dkc = 0; dkc < 4; ++dkc) {
        ushort4 r;
        r.x = f32_bf16(o[dkc][0] * inv);
        r.y = f32_bf16(o[dkc][1] * inv);
        r.z = f32_bf16(o[dkc][2] * inv);
        r.w = f32_bf16(o[dkc][3] * inv);
        *reinterpret_cast<ushort4*>(cp + dkc*16 + l4*4) = r;
    }
}

// ---------------- launch ----------------
// ws (ushorts): xb 4.19M | Wqkvt 1.57M | Wot 1.05M | Qb 4.19M | Kb 1.05M |
// Vbuf 1.05M = 13.1M ushorts = 25 MiB (same footprint as the proven layout).
// Ctx aliases xb (dead after the QKV GEMM).
extern "C" void kernel_launch(void* const* d_in, const int* in_sizes, int n_in,
                              void* d_out, int out_size, void* d_ws, size_t ws_size,
                              hipStream_t stream) {
    const float* x  = (const float*)d_in[0];
    const float* wq = (const float*)d_in[1];
    const float* wk = (const float*)d_in[2];
    const float* wv = (const float*)d_in[3];
    const float* wo = (const float*)d_in[4];
    float* out = (float*)d_out;

    const int M  = NBATCH * S_LEN;                  // 4096
    const int nX = M * DMODEL;                      // 4194304
    const int nQ = NBATCH * NHEAD * S_LEN * HDIM;   // 4194304
    const int nKV = NBATCH * NKV * S_LEN * HDIM;    // 1048576

    unsigned short* xb    = (unsigned short*)d_ws;
    unsigned short* Wqkvt = xb + nX;
    unsigned short* Wot   = Wqkvt + 1536 * 1024;
    unsigned short* Qb    = Wot + 1024 * 1024;
    unsigned short* Kb    = Qb + nQ;
    unsigned short* Vbuf  = Kb + nKV;
    unsigned short* Ctx   = xb;                     // alias

    cvt_bf16_k<<<nX / 1024, 256, 0, stream>>>(x, xb, nX / 4);
    cvtT_k<<<dim3(16, 16), 256, 0, stream>>>(wq, Wqkvt, 1024, 0);
    cvtT_k<<<dim3( 4, 16), 256, 0, stream>>>(wk, Wqkvt,  256, 1024);
    cvtT_k<<<dim3( 4, 16), 256, 0, stream>>>(wv, Wqkvt,  256, 1280);
    cvtT_k<<<dim3(16, 16), 256, 0, stream>>>(wo, Wot,   1024, 0);

    // fused QKV projection (rope, QSCALE, V^T) in one GEMM
    gemm2_k<1><<<dim3(1536/64, M/128), 256, 0, stream>>>(
        xb, Wqkvt, 1536, DMODEL, nullptr, Qb, Kb, Vbuf);

    attn_k<<<dim3(S_LEN/64, NHEAD, NBATCH), 256, 0, stream>>>(Qb, Kb, Vbuf, Ctx);

    // output projection -> f32
    gemm2_k<0><<<dim3(DMODEL/64, M/128), 256, 0, stream>>>(
        Ctx, Wot, DMODEL, DMODEL, out, nullptr, nullptr, nullptr);
}

// Round 8
// 128.887 us; speedup vs baseline: 3.0549x; 1.0734x over previous
//
#include <hip/hip_runtime.h>
#include <hip/hip_bf16.h>

#define S_LEN 2048
#define NBATCH 2
#define DMODEL 1024
#define NHEAD 16
#define NKV 4
#define HDIM 64

typedef __attribute__((ext_vector_type(4))) float f32x4;
typedef __attribute__((ext_vector_type(8))) short s16x8;

// 0.125 (1/sqrt(dk)) * log2(e): Q pre-scale so softmax runs in exp2 domain
#define QSCALE 0.18033688011112042f

__device__ __forceinline__ unsigned short f32_bf16(float f) {
    unsigned int u = __float_as_uint(f);
    u += 0x7FFFu + ((u >> 16) & 1u);
    return (unsigned short)(u >> 16);
}

// ---------------- f32 -> bf16 convert (x) ----------------
__global__ __launch_bounds__(256) void cvt_bf16_k(const float* __restrict__ in,
                                                  unsigned short* __restrict__ out, int n4) {
    int i = blockIdx.x * 256 + threadIdx.x;
    if (i < n4) {
        const float4 v = reinterpret_cast<const float4*>(in)[i];
        ushort4 r;
        r.x = f32_bf16(v.x); r.y = f32_bf16(v.y);
        r.z = f32_bf16(v.z); r.w = f32_bf16(v.w);
        reinterpret_cast<ushort4*>(out)[i] = r;
    }
}

// ---------------- f32 -> bf16 convert + TRANSPOSE (weights) ----------------
__global__ __launch_bounds__(256) void cvtT_k(const float* __restrict__ in,
                                              unsigned short* __restrict__ out,
                                              int N, int n_off) {
    __shared__ float t[64][65];
    const int n0  = blockIdx.x * 64;
    const int k0  = blockIdx.y * 64;
    const int tid = threadIdx.x;
    const int r   = tid >> 4;          // 0..15
    const int c4  = (tid & 15) * 4;    // 0..60
    #pragma unroll
    for (int i = 0; i < 4; ++i) {
        const float4 v = *reinterpret_cast<const float4*>(
            in + (size_t)(k0 + i*16 + r) * N + n0 + c4);
        t[i*16 + r][c4+0] = v.x; t[i*16 + r][c4+1] = v.y;
        t[i*16 + r][c4+2] = v.z; t[i*16 + r][c4+3] = v.w;
    }
    __syncthreads();
    #pragma unroll
    for (int i = 0; i < 4; ++i) {
        const int n = i*16 + r;
        ushort4 o;
        o.x = f32_bf16(t[c4+0][n]); o.y = f32_bf16(t[c4+1][n]);
        o.z = f32_bf16(t[c4+2][n]); o.w = f32_bf16(t[c4+3][n]);
        *reinterpret_cast<ushort4*>(out + (size_t)(n_off + n0 + n) * 1024 + k0 + c4) = o;
    }
}

// ---------------- GEMM2: C[M][N] = A[M][K] @ Bt[N][K]^T, bf16, f32 acc ----------------
// (unchanged from R7 — verified)
template<int EPI>
__global__ __launch_bounds__(256, 2) void gemm2_k(
    const unsigned short* __restrict__ A,
    const unsigned short* __restrict__ Bt,
    int N, int K,
    float* __restrict__ OutF,
    unsigned short* __restrict__ Qb,
    unsigned short* __restrict__ Kbuf,
    unsigned short* __restrict__ Vbuf)
{
    __shared__ unsigned short As[2][128 * 64];
    __shared__ unsigned short Bs[2][64 * 64];

    const int tid  = threadIdx.x;
    const int lane = tid & 63;
    const int l15  = lane & 15;
    const int l4   = lane >> 4;
    const int wave = tid >> 6;
    const int wm   = wave >> 1;
    const int wn   = wave & 1;
    const int bm   = blockIdx.y * 128;
    const int bn   = blockIdx.x * 64;

    f32x4 acc[4][2] = {};
    s16x8 ar[4], br[2];

    const int NT = K >> 6;

    #define GLOAD(k0)                                                              \
        {                                                                          \
            _Pragma("unroll")                                                      \
            for (int p = 0; p < 4; ++p) {                                          \
                const int c = p*256 + tid, r_ = c >> 3, s_ = c & 7;                \
                ar[p] = *reinterpret_cast<const s16x8*>(                           \
                    A + (size_t)(bm + r_) * K + (k0) + s_*8);                      \
            }                                                                      \
            _Pragma("unroll")                                                      \
            for (int p = 0; p < 2; ++p) {                                          \
                const int c = p*256 + tid, r_ = c >> 3, s_ = c & 7;                \
                br[p] = *reinterpret_cast<const s16x8*>(                           \
                    Bt + (size_t)(bn + r_) * K + (k0) + s_*8);                     \
            }                                                                      \
        }
    #define LWRITE(buf)                                                            \
        {                                                                          \
            _Pragma("unroll")                                                      \
            for (int p = 0; p < 4; ++p) {                                          \
                const int c = p*256 + tid, r_ = c >> 3, s_ = c & 7;                \
                *reinterpret_cast<s16x8*>(                                         \
                    &As[buf][r_*64 + ((s_ ^ (r_ & 7)) * 8)]) = ar[p];              \
            }                                                                      \
            _Pragma("unroll")                                                      \
            for (int p = 0; p < 2; ++p) {                                          \
                const int c = p*256 + tid, r_ = c >> 3, s_ = c & 7;                \
                *reinterpret_cast<s16x8*>(                                         \
                    &Bs[buf][r_*64 + ((s_ ^ (r_ & 7)) * 8)]) = br[p];              \
            }                                                                      \
        }

    GLOAD(0); LWRITE(0); __syncthreads();

    for (int kt = 0; kt < NT; ++kt) {
        const int cur = kt & 1;
        if (kt + 1 < NT) GLOAD((kt + 1) << 6);
        #pragma unroll
        for (int ks = 0; ks < 2; ++ks) {
            s16x8 af[4], bfv[2];
            #pragma unroll
            for (int mi = 0; mi < 4; ++mi) {
                const int r = wm*64 + mi*16 + l15;
                af[mi] = *reinterpret_cast<const s16x8*>(
                    &As[cur][r*64 + (((ks*4 + l4) ^ (r & 7)) * 8)]);
            }
            #pragma unroll
            for (int nj = 0; nj < 2; ++nj) {
                const int r = wn*32 + nj*16 + l15;
                bfv[nj] = *reinterpret_cast<const s16x8*>(
                    &Bs[cur][r*64 + (((ks*4 + l4) ^ (r & 7)) * 8)]);
            }
            #pragma unroll
            for (int mi = 0; mi < 4; ++mi)
                #pragma unroll
                for (int nj = 0; nj < 2; ++nj)
                    acc[mi][nj] = __builtin_amdgcn_mfma_f32_16x16x32_bf16(
                        af[mi], bfv[nj], acc[mi][nj], 0, 0, 0);
        }
        if (kt + 1 < NT) LWRITE(cur ^ 1);
        __syncthreads();
    }
    #undef GLOAD
    #undef LWRITE

    #pragma unroll
    for (int mi = 0; mi < 4; ++mi) {
        #pragma unroll
        for (int nj = 0; nj < 2; ++nj) {
            #pragma unroll
            for (int v = 0; v < 4; ++v) {
                const int gr = bm + wm*64 + mi*16 + l4*4 + v;
                const int gc = bn + wn*32 + nj*16 + l15;
                float val = acc[mi][nj][v];
                if (EPI == 0) {
                    OutF[(size_t)gr * N + gc] = val;
                } else {
                    const int b  = gr >> 11;
                    const int sr = gr & (S_LEN - 1);
                    const int dk = gc & 63;
                    if (bn < 1024) {                   // Q: rope + QSCALE
                        const float partner = __shfl_xor(val, 1, 64);
                        const int   jp  = dk >> 1;
                        const float inv = __expf((float)jp * (-2.0f / 64.0f) * 9.210340371976184f);
                        const int   hh  = gc >> 6;
                        float sn, cs;
                        __sincosf((float)hh * inv, &sn, &cs);
                        val = ((gc & 1) == 0) ? (val * cs - partner * sn)
                                              : (partner * sn + val * cs);
                        val *= QSCALE;
                        Qb[(((size_t)b * NHEAD + hh) * S_LEN + sr) * HDIM + dk] = f32_bf16(val);
                    } else if (bn < 1280) {            // K: rope (kv-head index)
                        const float partner = __shfl_xor(val, 1, 64);
                        const int   jp  = dk >> 1;
                        const float inv = __expf((float)jp * (-2.0f / 64.0f) * 9.210340371976184f);
                        const int   hh  = (gc - 1024) >> 6;
                        float sn, cs;
                        __sincosf((float)hh * inv, &sn, &cs);
                        val = ((gc & 1) == 0) ? (val * cs - partner * sn)
                                              : (partner * sn + val * cs);
                        Kbuf[(((size_t)b * NKV + hh) * S_LEN + sr) * HDIM + dk] = f32_bf16(val);
                    } else {                           // V: transposed [dk][s]
                        const int hh = (gc - 1280) >> 6;
                        Vbuf[(((size_t)b * NKV + hh) * HDIM + dk) * S_LEN + sr] = f32_bf16(val);
                    }
                }
            }
        }
    }
}

// ---------------- flash attention (causal, GQA), LDS-staged K/V ----------------
// 8 waves x 16 q-rows = 128 q-rows per block; K/V staged once per 128 rows.
// Per-wave diagonal tile dt = qb>>6: t<dt full, t==dt masked, t>dt skip
// (wave-uniform branch; every wave executes the barrier every iteration).

__device__ __forceinline__ void stage_load(
    const unsigned short* __restrict__ Kp,
    const unsigned short* __restrict__ Vp,
    int kv0, int tid, s16x8& kr, s16x8& vr)
{
    const int r = tid >> 3, col = (tid & 7) * 8;   // 512 chunks of 16B per tile
    kr = *reinterpret_cast<const s16x8*>(Kp + (size_t)(kv0 + r) * HDIM + col);
    vr = *reinterpret_cast<const s16x8*>(Vp + (size_t)r * S_LEN + kv0 + col);
}

__device__ __forceinline__ void stage_write(
    unsigned short (*Ksb)[72], unsigned short (*Vsb)[72],
    int tid, const s16x8& kr, const s16x8& vr)
{
    const int r = tid >> 3, col = (tid & 7) * 8;
    *reinterpret_cast<s16x8*>(&Ksb[r][col]) = kr;
    *reinterpret_cast<s16x8*>(&Vsb[r][col]) = vr;
}

template<bool MASK>
__device__ __forceinline__ void attn_compute(
    int l15, int l4, int wloc,
    const unsigned short (*Ksb)[72], const unsigned short (*Vsb)[72],
    const s16x8 qf[2], f32x4 o[4], float& m, float& lsum,
    unsigned short (*Plds)[72])
{
    f32x4 s[4] = {};
    #pragma unroll
    for (int c = 0; c < 4; ++c)
        #pragma unroll
        for (int ks = 0; ks < 2; ++ks) {
            const s16x8 kf = *reinterpret_cast<const s16x8*>(&Ksb[c*16 + l15][ks*32 + l4*8]);
            s[c] = __builtin_amdgcn_mfma_f32_16x16x32_bf16(kf, qf[ks], s[c], 0, 0, 0);
        }

    if (MASK) {
        const int qloc = wloc + l15;     // q row within this wave's 16, kv within tile
        #pragma unroll
        for (int c = 0; c < 4; ++c)
            #pragma unroll
            for (int v = 0; v < 4; ++v) {
                const int kvloc = c*16 + l4*4 + v;
                s[c][v] = (kvloc <= qloc) ? s[c][v] : -1e30f;
            }
    }

    float mx = -1e30f;
    #pragma unroll
    for (int c = 0; c < 4; ++c)
        #pragma unroll
        for (int v = 0; v < 4; ++v) mx = fmaxf(mx, s[c][v]);
    mx = fmaxf(mx, __shfl_xor(mx, 16, 64));
    mx = fmaxf(mx, __shfl_xor(mx, 32, 64));
    const float mnew  = fmaxf(m, mx);
    const float scale = __builtin_amdgcn_exp2f(m - mnew);
    float psum = 0.0f;
    #pragma unroll
    for (int c = 0; c < 4; ++c)
        #pragma unroll
        for (int v = 0; v < 4; ++v) {
            const float p = __builtin_amdgcn_exp2f(s[c][v] - mnew);
            s[c][v] = p;
            psum += p;
        }
    psum += __shfl_xor(psum, 16, 64);
    psum += __shfl_xor(psum, 32, 64);
    lsum = lsum * scale + psum;
    m = mnew;
    #pragma unroll
    for (int dkc = 0; dkc < 4; ++dkc) o[dkc] *= scale;

    #pragma unroll
    for (int c = 0; c < 4; ++c) {
        uint2 w;
        w.x = (unsigned int)f32_bf16(s[c][0]) | ((unsigned int)f32_bf16(s[c][1]) << 16);
        w.y = (unsigned int)f32_bf16(s[c][2]) | ((unsigned int)f32_bf16(s[c][3]) << 16);
        *reinterpret_cast<uint2*>(&Plds[l15][c*16 + l4*4]) = w;
    }
    s16x8 pb[2];
    #pragma unroll
    for (int ks = 0; ks < 2; ++ks)
        pb[ks] = *reinterpret_cast<const s16x8*>(&Plds[l15][ks*32 + l4*8]);

    #pragma unroll
    for (int dkc = 0; dkc < 4; ++dkc)
        #pragma unroll
        for (int ks = 0; ks < 2; ++ks) {
            const s16x8 vf = *reinterpret_cast<const s16x8*>(&Vsb[dkc*16 + l15][ks*32 + l4*8]);
            o[dkc] = __builtin_amdgcn_mfma_f32_16x16x32_bf16(vf, pb[ks], o[dkc], 0, 0, 0);
        }
}

__global__ __launch_bounds__(512, 2) void attn_k(
    const unsigned short* __restrict__ Q,
    const unsigned short* __restrict__ Kb,
    const unsigned short* __restrict__ Vt,
    unsigned short* __restrict__ Ctx)
{
    __shared__ unsigned short Ks[2][64][72];    // K tile double-buffer [kv][dk]
    __shared__ unsigned short Vs[2][64][72];    // V^T tile double-buffer [dk][kv]
    __shared__ unsigned short Plds[8][16][72];  // per-wave P tile [q16][kv64]

    const int tid  = threadIdx.x;
    const int lane = tid & 63;
    const int l15  = lane & 15;
    const int l4   = lane >> 4;
    const int wave = tid >> 6;

    // reversed order: biggest causal blocks launch first (LPT)
    const int qb0 = (gridDim.x - 1 - blockIdx.x) * 128;
    const int h   = blockIdx.y;
    const int b   = blockIdx.z;
    const int g   = h >> 2;   // kv head

    const unsigned short* Qp = Q  + ((size_t)b * NHEAD + h) * S_LEN * HDIM;
    const unsigned short* Kp = Kb + ((size_t)b * NKV  + g) * S_LEN * HDIM;
    const unsigned short* Vp = Vt + ((size_t)b * NKV  + g) * HDIM * S_LEN;

    const int qb = qb0 + wave * 16;   // this wave's 16 q-rows
    const int dt = qb >> 6;           // wave's diagonal kv-tile
    const int NT = (qb0 >> 7) * 2 + 2; // kv tiles for this block

    s16x8 qf[2];
    #pragma unroll
    for (int ks = 0; ks < 2; ++ks)
        qf[ks] = *reinterpret_cast<const s16x8*>(Qp + (size_t)(qb + l15) * HDIM + ks*32 + l4*8);

    f32x4 o[4] = {};
    float m = -1e30f, lsum = 0.0f;

    // prologue: tile 0 -> buf 0
    {
        s16x8 kr, vr;
        stage_load(Kp, Vp, 0, tid, kr, vr);
        stage_write(Ks[0], Vs[0], tid, kr, vr);
        __syncthreads();
    }

    for (int t = 0; t < NT; ++t) {
        const int cur = t & 1;
        s16x8 kr, vr;
        const bool more = (t + 1 < NT);
        if (more) stage_load(Kp, Vp, (t + 1) * 64, tid, kr, vr);   // issue early
        if (t < dt)
            attn_compute<false>(l15, l4, wave*16 - t*64 + qb0, Ks[cur], Vs[cur], qf, o, m, lsum, Plds[wave]);
        else if (t == dt)
            attn_compute<true >(l15, l4, wave*16 - t*64 + qb0, Ks[cur], Vs[cur], qf, o, m, lsum, Plds[wave]);
        // t > dt: this wave's rows are all masked out -> skip compute
        if (more) stage_write(Ks[cur ^ 1], Vs[cur ^ 1], tid, kr, vr); // vmcnt waits here
        __syncthreads();
    }

    // ---- normalize + store ctx [B][S][NHEAD][DK] bf16 (q = l15) ----
    const float inv = 1.0f / lsum;
    unsigned short* cp = Ctx + (((size_t)b * S_LEN + qb + l15) * NHEAD + h) * HDIM;
    #pragma unroll
    for (int dkc = 0; dkc < 4; ++dkc) {
        ushort4 r;
        r.x = f32_bf16(o[dkc][0] * inv);
        r.y = f32_bf16(o[dkc][1] * inv);
        r.z = f32_bf16(o[dkc][2] * inv);
        r.w = f32_bf16(o[dkc][3] * inv);
        *reinterpret_cast<ushort4*>(cp + dkc*16 + l4*4) = r;
    }
}

// ---------------- launch ----------------
// ws (ushorts): xb 4.19M | Wqkvt 1.57M | Wot 1.05M | Qb 4.19M | Kb 1.05M |
// Vbuf 1.05M = 13.1M ushorts = 25 MiB. Ctx aliases xb (dead after QKV GEMM).
extern "C" void kernel_launch(void* const* d_in, const int* in_sizes, int n_in,
                              void* d_out, int out_size, void* d_ws, size_t ws_size,
                              hipStream_t stream) {
    const float* x  = (const float*)d_in[0];
    const float* wq = (const float*)d_in[1];
    const float* wk = (const float*)d_in[2];
    const float* wv = (const float*)d_in[3];
    const float* wo = (const float*)d_in[4];
    float* out = (float*)d_out;

    const int M  = NBATCH * S_LEN;                  // 4096
    const int nX = M * DMODEL;                      // 4194304
    const int nQ = NBATCH * NHEAD * S_LEN * HDIM;   // 4194304
    const int nKV = NBATCH * NKV * S_LEN * HDIM;    // 1048576

    unsigned short* xb    = (unsigned short*)d_ws;
    unsigned short* Wqkvt = xb + nX;
    unsigned short* Wot   = Wqkvt + 1536 * 1024;
    unsigned short* Qb    = Wot + 1024 * 1024;
    unsigned short* Kb    = Qb + nQ;
    unsigned short* Vbuf  = Kb + nKV;
    unsigned short* Ctx   = xb;                     // alias

    cvt_bf16_k<<<nX / 1024, 256, 0, stream>>>(x, xb, nX / 4);
    cvtT_k<<<dim3(16, 16), 256, 0, stream>>>(wq, Wqkvt, 1024, 0);
    cvtT_k<<<dim3( 4, 16), 256, 0, stream>>>(wk, Wqkvt,  256, 1024);
    cvtT_k<<<dim3( 4, 16), 256, 0, stream>>>(wv, Wqkvt,  256, 1280);
    cvtT_k<<<dim3(16, 16), 256, 0, stream>>>(wo, Wot,   1024, 0);

    // fused QKV projection (rope, QSCALE, V^T) in one GEMM
    gemm2_k<1><<<dim3(1536/64, M/128), 256, 0, stream>>>(
        xb, Wqkvt, 1536, DMODEL, nullptr, Qb, Kb, Vbuf);

    attn_k<<<dim3(S_LEN/128, NHEAD, NBATCH), 512, 0, stream>>>(Qb, Kb, Vbuf, Ctx);

    // output projection -> f32
    gemm2_k<0><<<dim3(DMODEL/64, M/128), 256, 0, stream>>>(
        Ctx, Wot, DMODEL, DMODEL, out, nullptr, nullptr, nullptr);
}

// Round 9
// 113.070 us; speedup vs baseline: 3.4823x; 1.1399x over previous
//
#include <hip/hip_runtime.h>
#include <hip/hip_bf16.h>

#define S_LEN 2048
#define NBATCH 2
#define DMODEL 1024
#define NHEAD 16
#define NKV 4
#define HDIM 64

typedef __attribute__((ext_vector_type(4))) float f32x4;
typedef __attribute__((ext_vector_type(8))) short s16x8;

// 0.125 (1/sqrt(dk)) * log2(e): Q pre-scale so softmax runs in exp2 domain
#define QSCALE 0.18033688011112042f

__device__ __forceinline__ unsigned short f32_bf16(float f) {
    unsigned int u = __float_as_uint(f);
    u += 0x7FFFu + ((u >> 16) & 1u);
    return (unsigned short)(u >> 16);
}

// ---------------- f32 -> bf16 convert (x) ----------------
__global__ __launch_bounds__(256) void cvt_bf16_k(const float* __restrict__ in,
                                                  unsigned short* __restrict__ out, int n4) {
    int i = blockIdx.x * 256 + threadIdx.x;
    if (i < n4) {
        const float4 v = reinterpret_cast<const float4*>(in)[i];
        ushort4 r;
        r.x = f32_bf16(v.x); r.y = f32_bf16(v.y);
        r.z = f32_bf16(v.z); r.w = f32_bf16(v.w);
        reinterpret_cast<ushort4*>(out)[i] = r;
    }
}

// ---------------- f32 -> bf16 convert + TRANSPOSE (weights) ----------------
__global__ __launch_bounds__(256) void cvtT_k(const float* __restrict__ in,
                                              unsigned short* __restrict__ out,
                                              int N, int n_off) {
    __shared__ float t[64][65];
    const int n0  = blockIdx.x * 64;
    const int k0  = blockIdx.y * 64;
    const int tid = threadIdx.x;
    const int r   = tid >> 4;          // 0..15
    const int c4  = (tid & 15) * 4;    // 0..60
    #pragma unroll
    for (int i = 0; i < 4; ++i) {
        const float4 v = *reinterpret_cast<const float4*>(
            in + (size_t)(k0 + i*16 + r) * N + n0 + c4);
        t[i*16 + r][c4+0] = v.x; t[i*16 + r][c4+1] = v.y;
        t[i*16 + r][c4+2] = v.z; t[i*16 + r][c4+3] = v.w;
    }
    __syncthreads();
    #pragma unroll
    for (int i = 0; i < 4; ++i) {
        const int n = i*16 + r;
        ushort4 o;
        o.x = f32_bf16(t[c4+0][n]); o.y = f32_bf16(t[c4+1][n]);
        o.z = f32_bf16(t[c4+2][n]); o.w = f32_bf16(t[c4+3][n]);
        *reinterpret_cast<ushort4*>(out + (size_t)(n_off + n0 + n) * 1024 + k0 + c4) = o;
    }
}

// ---------------- GEMM2: C[M][N] = A[M][K] @ Bt[N][K]^T, bf16, f32 acc ----------------
// (unchanged from R7 — verified)
template<int EPI>
__global__ __launch_bounds__(256, 2) void gemm2_k(
    const unsigned short* __restrict__ A,
    const unsigned short* __restrict__ Bt,
    int N, int K,
    float* __restrict__ OutF,
    unsigned short* __restrict__ Qb,
    unsigned short* __restrict__ Kbuf,
    unsigned short* __restrict__ Vbuf)
{
    __shared__ unsigned short As[2][128 * 64];
    __shared__ unsigned short Bs[2][64 * 64];

    const int tid  = threadIdx.x;
    const int lane = tid & 63;
    const int l15  = lane & 15;
    const int l4   = lane >> 4;
    const int wave = tid >> 6;
    const int wm   = wave >> 1;
    const int wn   = wave & 1;
    const int bm   = blockIdx.y * 128;
    const int bn   = blockIdx.x * 64;

    f32x4 acc[4][2] = {};
    s16x8 ar[4], br[2];

    const int NT = K >> 6;

    #define GLOAD(k0)                                                              \
        {                                                                          \
            _Pragma("unroll")                                                      \
            for (int p = 0; p < 4; ++p) {                                          \
                const int c = p*256 + tid, r_ = c >> 3, s_ = c & 7;                \
                ar[p] = *reinterpret_cast<const s16x8*>(                           \
                    A + (size_t)(bm + r_) * K + (k0) + s_*8);                      \
            }                                                                      \
            _Pragma("unroll")                                                      \
            for (int p = 0; p < 2; ++p) {                                          \
                const int c = p*256 + tid, r_ = c >> 3, s_ = c & 7;                \
                br[p] = *reinterpret_cast<const s16x8*>(                           \
                    Bt + (size_t)(bn + r_) * K + (k0) + s_*8);                     \
            }                                                                      \
        }
    #define LWRITE(buf)                                                            \
        {                                                                          \
            _Pragma("unroll")                                                      \
            for (int p = 0; p < 4; ++p) {                                          \
                const int c = p*256 + tid, r_ = c >> 3, s_ = c & 7;                \
                *reinterpret_cast<s16x8*>(                                         \
                    &As[buf][r_*64 + ((s_ ^ (r_ & 7)) * 8)]) = ar[p];              \
            }                                                                      \
            _Pragma("unroll")                                                      \
            for (int p = 0; p < 2; ++p) {                                          \
                const int c = p*256 + tid, r_ = c >> 3, s_ = c & 7;                \
                *reinterpret_cast<s16x8*>(                                         \
                    &Bs[buf][r_*64 + ((s_ ^ (r_ & 7)) * 8)]) = br[p];              \
            }                                                                      \
        }

    GLOAD(0); LWRITE(0); __syncthreads();

    for (int kt = 0; kt < NT; ++kt) {
        const int cur = kt & 1;
        if (kt + 1 < NT) GLOAD((kt + 1) << 6);
        #pragma unroll
        for (int ks = 0; ks < 2; ++ks) {
            s16x8 af[4], bfv[2];
            #pragma unroll
            for (int mi = 0; mi < 4; ++mi) {
                const int r = wm*64 + mi*16 + l15;
                af[mi] = *reinterpret_cast<const s16x8*>(
                    &As[cur][r*64 + (((ks*4 + l4) ^ (r & 7)) * 8)]);
            }
            #pragma unroll
            for (int nj = 0; nj < 2; ++nj) {
                const int r = wn*32 + nj*16 + l15;
                bfv[nj] = *reinterpret_cast<const s16x8*>(
                    &Bs[cur][r*64 + (((ks*4 + l4) ^ (r & 7)) * 8)]);
            }
            #pragma unroll
            for (int mi = 0; mi < 4; ++mi)
                #pragma unroll
                for (int nj = 0; nj < 2; ++nj)
                    acc[mi][nj] = __builtin_amdgcn_mfma_f32_16x16x32_bf16(
                        af[mi], bfv[nj], acc[mi][nj], 0, 0, 0);
        }
        if (kt + 1 < NT) LWRITE(cur ^ 1);
        __syncthreads();
    }
    #undef GLOAD
    #undef LWRITE

    #pragma unroll
    for (int mi = 0; mi < 4; ++mi) {
        #pragma unroll
        for (int nj = 0; nj < 2; ++nj) {
            #pragma unroll
            for (int v = 0; v < 4; ++v) {
                const int gr = bm + wm*64 + mi*16 + l4*4 + v;
                const int gc = bn + wn*32 + nj*16 + l15;
                float val = acc[mi][nj][v];
                if (EPI == 0) {
                    OutF[(size_t)gr * N + gc] = val;
                } else {
                    const int b  = gr >> 11;
                    const int sr = gr & (S_LEN - 1);
                    const int dk = gc & 63;
                    if (bn < 1024) {                   // Q: rope + QSCALE
                        const float partner = __shfl_xor(val, 1, 64);
                        const int   jp  = dk >> 1;
                        const float inv = __expf((float)jp * (-2.0f / 64.0f) * 9.210340371976184f);
                        const int   hh  = gc >> 6;
                        float sn, cs;
                        __sincosf((float)hh * inv, &sn, &cs);
                        val = ((gc & 1) == 0) ? (val * cs - partner * sn)
                                              : (partner * sn + val * cs);
                        val *= QSCALE;
                        Qb[(((size_t)b * NHEAD + hh) * S_LEN + sr) * HDIM + dk] = f32_bf16(val);
                    } else if (bn < 1280) {            // K: rope (kv-head index)
                        const float partner = __shfl_xor(val, 1, 64);
                        const int   jp  = dk >> 1;
                        const float inv = __expf((float)jp * (-2.0f / 64.0f) * 9.210340371976184f);
                        const int   hh  = (gc - 1024) >> 6;
                        float sn, cs;
                        __sincosf((float)hh * inv, &sn, &cs);
                        val = ((gc & 1) == 0) ? (val * cs - partner * sn)
                                              : (partner * sn + val * cs);
                        Kbuf[(((size_t)b * NKV + hh) * S_LEN + sr) * HDIM + dk] = f32_bf16(val);
                    } else {                           // V: transposed [dk][s]
                        const int hh = (gc - 1280) >> 6;
                        Vbuf[(((size_t)b * NKV + hh) * HDIM + dk) * S_LEN + sr] = f32_bf16(val);
                    }
                }
            }
        }
    }
}

// ---------------- flash attention (causal, GQA), LDS-staged K/V ----------------
// 8 waves x 16 q-rows = 128 q-rows per block. Linear grid with complement
// pairing: blocks L and L+256 (same CU under round-robin dispatch) get
// q-tiles (15-p, p) so every CU's stage total ~= 34. Per-lane partial lsum
// (cross-lane reduce deferred to epilogue). setprio(1) around MFMA clusters.

__device__ __forceinline__ void stage_load(
    const unsigned short* __restrict__ Kp,
    const unsigned short* __restrict__ Vp,
    int kv0, int tid, s16x8& kr, s16x8& vr)
{
    const int r = tid >> 3, col = (tid & 7) * 8;   // 512 chunks of 16B per tile
    kr = *reinterpret_cast<const s16x8*>(Kp + (size_t)(kv0 + r) * HDIM + col);
    vr = *reinterpret_cast<const s16x8*>(Vp + (size_t)r * S_LEN + kv0 + col);
}

__device__ __forceinline__ void stage_write(
    unsigned short (*Ksb)[72], unsigned short (*Vsb)[72],
    int tid, const s16x8& kr, const s16x8& vr)
{
    const int r = tid >> 3, col = (tid & 7) * 8;
    *reinterpret_cast<s16x8*>(&Ksb[r][col]) = kr;
    *reinterpret_cast<s16x8*>(&Vsb[r][col]) = vr;
}

template<bool MASK>
__device__ __forceinline__ void attn_compute(
    int l15, int l4, int wloc,
    const unsigned short (*Ksb)[72], const unsigned short (*Vsb)[72],
    const s16x8 qf[2], f32x4 o[4], float& m, float& lsum,
    unsigned short (*Plds)[72])
{
    f32x4 s[4] = {};
    __builtin_amdgcn_s_setprio(1);
    #pragma unroll
    for (int c = 0; c < 4; ++c)
        #pragma unroll
        for (int ks = 0; ks < 2; ++ks) {
            const s16x8 kf = *reinterpret_cast<const s16x8*>(&Ksb[c*16 + l15][ks*32 + l4*8]);
            s[c] = __builtin_amdgcn_mfma_f32_16x16x32_bf16(kf, qf[ks], s[c], 0, 0, 0);
        }
    __builtin_amdgcn_s_setprio(0);

    if (MASK) {
        const int qloc = wloc + l15;     // q row within tile; kv within tile
        #pragma unroll
        for (int c = 0; c < 4; ++c)
            #pragma unroll
            for (int v = 0; v < 4; ++v) {
                const int kvloc = c*16 + l4*4 + v;
                s[c][v] = (kvloc <= qloc) ? s[c][v] : -1e30f;
            }
    }

    // ---- online softmax: cross-lane max (needed for consistent P), per-lane lsum ----
    float mx = -1e30f;
    #pragma unroll
    for (int c = 0; c < 4; ++c)
        #pragma unroll
        for (int v = 0; v < 4; ++v) mx = fmaxf(mx, s[c][v]);
    mx = fmaxf(mx, __shfl_xor(mx, 16, 64));
    mx = fmaxf(mx, __shfl_xor(mx, 32, 64));
    const float mnew  = fmaxf(m, mx);
    const float scale = __builtin_amdgcn_exp2f(m - mnew);
    float psum = 0.0f;
    #pragma unroll
    for (int c = 0; c < 4; ++c)
        #pragma unroll
        for (int v = 0; v < 4; ++v) {
            const float p = __builtin_amdgcn_exp2f(s[c][v] - mnew);
            s[c][v] = p;
            psum += p;
        }
    lsum = lsum * scale + psum;          // per-lane partial; reduce at end
    m = mnew;
    #pragma unroll
    for (int dkc = 0; dkc < 4; ++dkc) o[dkc] *= scale;

    #pragma unroll
    for (int c = 0; c < 4; ++c) {
        uint2 w;
        w.x = (unsigned int)f32_bf16(s[c][0]) | ((unsigned int)f32_bf16(s[c][1]) << 16);
        w.y = (unsigned int)f32_bf16(s[c][2]) | ((unsigned int)f32_bf16(s[c][3]) << 16);
        *reinterpret_cast<uint2*>(&Plds[l15][c*16 + l4*4]) = w;
    }
    s16x8 pb[2];
    #pragma unroll
    for (int ks = 0; ks < 2; ++ks)
        pb[ks] = *reinterpret_cast<const s16x8*>(&Plds[l15][ks*32 + l4*8]);

    __builtin_amdgcn_s_setprio(1);
    #pragma unroll
    for (int dkc = 0; dkc < 4; ++dkc)
        #pragma unroll
        for (int ks = 0; ks < 2; ++ks) {
            const s16x8 vf = *reinterpret_cast<const s16x8*>(&Vsb[dkc*16 + l15][ks*32 + l4*8]);
            o[dkc] = __builtin_amdgcn_mfma_f32_16x16x32_bf16(vf, pb[ks], o[dkc], 0, 0, 0);
        }
    __builtin_amdgcn_s_setprio(0);
}

__global__ __launch_bounds__(512, 2) void attn_k(
    const unsigned short* __restrict__ Q,
    const unsigned short* __restrict__ Kb,
    const unsigned short* __restrict__ Vt,
    unsigned short* __restrict__ Ctx)
{
    __shared__ unsigned short Ks[2][64][72];    // K tile double-buffer [kv][dk]
    __shared__ unsigned short Vs[2][64][72];    // V^T tile double-buffer [dk][kv]
    __shared__ unsigned short Plds[8][16][72];  // per-wave P tile [q16][kv64]

    const int tid  = threadIdx.x;
    const int lane = tid & 63;
    const int l15  = lane & 15;
    const int l4   = lane >> 4;
    const int wave = tid >> 6;

    // complement pairing: L and L+256 share a CU (round-robin dispatch),
    // and get q-tiles (15-p) and p -> per-CU stage total ~constant.
    const int L  = blockIdx.x;
    const int h  = L & 15;
    const int b  = (L >> 4) & 1;
    const int p  = (L >> 5) & 7;
    const int qt = (L < 256) ? (15 - p) : p;
    const int qb0 = qt * 128;

    const int g   = h >> 2;   // kv head

    const unsigned short* Qp = Q  + ((size_t)b * NHEAD + h) * S_LEN * HDIM;
    const unsigned short* Kp = Kb + ((size_t)b * NKV  + g) * S_LEN * HDIM;
    const unsigned short* Vp = Vt + ((size_t)b * NKV  + g) * HDIM * S_LEN;

    const int qb = qb0 + wave * 16;   // this wave's 16 q-rows
    const int dt = qb >> 6;           // wave's diagonal kv-tile
    const int NT = qt * 2 + 2;        // kv tiles for this block

    s16x8 qf[2];
    #pragma unroll
    for (int ks = 0; ks < 2; ++ks)
        qf[ks] = *reinterpret_cast<const s16x8*>(Qp + (size_t)(qb + l15) * HDIM + ks*32 + l4*8);

    f32x4 o[4] = {};
    float m = -1e30f, lsum = 0.0f;

    // prologue: tile 0 -> buf 0
    {
        s16x8 kr, vr;
        stage_load(Kp, Vp, 0, tid, kr, vr);
        stage_write(Ks[0], Vs[0], tid, kr, vr);
        __syncthreads();
    }

    for (int t = 0; t < NT; ++t) {
        const int cur = t & 1;
        s16x8 kr, vr;
        const bool more = (t + 1 < NT);
        if (more) stage_load(Kp, Vp, (t + 1) * 64, tid, kr, vr);   // issue early
        if (t < dt)
            attn_compute<false>(l15, l4, wave*16 - t*64 + qb0, Ks[cur], Vs[cur], qf, o, m, lsum, Plds[wave]);
        else if (t == dt)
            attn_compute<true >(l15, l4, wave*16 - t*64 + qb0, Ks[cur], Vs[cur], qf, o, m, lsum, Plds[wave]);
        // t > dt: this wave's rows are all masked out -> skip compute
        if (more) stage_write(Ks[cur ^ 1], Vs[cur ^ 1], tid, kr, vr); // vmcnt waits here
        __syncthreads();
    }

    // ---- deferred lsum cross-lane reduce + normalize + store ----
    lsum += __shfl_xor(lsum, 16, 64);
    lsum += __shfl_xor(lsum, 32, 64);
    const float inv = 1.0f / lsum;
    unsigned short* cp = Ctx + (((size_t)b * S_LEN + qb + l15) * NHEAD + h) * HDIM;
    #pragma unroll
    for (int dkc = 0; dkc < 4; ++dkc) {
        ushort4 r;
        r.x = f32_bf16(o[dkc][0] * inv);
        r.y = f32_bf16(o[dkc][1] * inv);
        r.z = f32_bf16(o[dkc][2] * inv);
        r.w = f32_bf16(o[dkc][3] * inv);
        *reinterpret_cast<ushort4*>(cp + dkc*16 + l4*4) = r;
    }
}

// ---------------- launch ----------------
// ws (ushorts): xb 4.19M | Wqkvt 1.57M | Wot 1.05M | Qb 4.19M | Kb 1.05M |
// Vbuf 1.05M = 13.1M ushorts = 25 MiB. Ctx aliases xb (dead after QKV GEMM).
extern "C" void kernel_launch(void* const* d_in, const int* in_sizes, int n_in,
                              void* d_out, int out_size, void* d_ws, size_t ws_size,
                              hipStream_t stream) {
    const float* x  = (const float*)d_in[0];
    const float* wq = (const float*)d_in[1];
    const float* wk = (const float*)d_in[2];
    const float* wv = (const float*)d_in[3];
    const float* wo = (const float*)d_in[4];
    float* out = (float*)d_out;

    const int M  = NBATCH * S_LEN;                  // 4096
    const int nX = M * DMODEL;                      // 4194304
    const int nQ = NBATCH * NHEAD * S_LEN * HDIM;   // 4194304
    const int nKV = NBATCH * NKV * S_LEN * HDIM;    // 1048576

    unsigned short* xb    = (unsigned short*)d_ws;
    unsigned short* Wqkvt = xb + nX;
    unsigned short* Wot   = Wqkvt + 1536 * 1024;
    unsigned short* Qb    = Wot + 1024 * 1024;
    unsigned short* Kb    = Qb + nQ;
    unsigned short* Vbuf  = Kb + nKV;
    unsigned short* Ctx   = xb;                     // alias

    cvt_bf16_k<<<nX / 1024, 256, 0, stream>>>(x, xb, nX / 4);
    cvtT_k<<<dim3(16, 16), 256, 0, stream>>>(wq, Wqkvt, 1024, 0);
    cvtT_k<<<dim3( 4, 16), 256, 0, stream>>>(wk, Wqkvt,  256, 1024);
    cvtT_k<<<dim3( 4, 16), 256, 0, stream>>>(wv, Wqkvt,  256, 1280);
    cvtT_k<<<dim3(16, 16), 256, 0, stream>>>(wo, Wot,   1024, 0);

    // fused QKV projection (rope, QSCALE, V^T) in one GEMM
    gemm2_k<1><<<dim3(1536/64, M/128), 256, 0, stream>>>(
        xb, Wqkvt, 1536, DMODEL, nullptr, Qb, Kb, Vbuf);

    attn_k<<<dim3(512, 1, 1), 512, 0, stream>>>(Qb, Kb, Vbuf, Ctx);

    // output projection -> f32
    gemm2_k<0><<<dim3(DMODEL/64, M/128), 256, 0, stream>>>(
        Ctx, Wot, DMODEL, DMODEL, out, nullptr, nullptr, nullptr);
}